// Round 4
// baseline (102.034 us; speedup 1.0000x reference)
//
#include <hip/hip_runtime.h>
#include <math.h>

#define NUSER 100000
#define NITEM 50000
#define NID   (NUSER + NITEM)
#define DIM_E 128
#define DIM_F 256
#define BATCH 1024
#define NCOL 128            /* 1 + NUM_NEG */
#define FLAT (BATCH * NCOL)

typedef __attribute__((ext_vector_type(8))) short bf16x8;
typedef __attribute__((ext_vector_type(4))) short bf16x4;
typedef __attribute__((ext_vector_type(4))) float f32x4;

__device__ __forceinline__ float dot4(float4 a, float4 b) {
    return a.x * b.x + a.y * b.y + a.z * b.z + a.w * b.w;
}

__device__ __forceinline__ short f2bf(float x) {
    unsigned u = __float_as_uint(x);
    unsigned r = (u + 0x7FFFu + ((u >> 16) & 1u)) >> 16;
    return (short)r;
}

__device__ __forceinline__ float bf2f(short s) {
    return __uint_as_float(((unsigned)(unsigned short)s) << 16);
}

__global__ __launch_bounds__(256) void zero_flags_kernel(int* __restrict__ flags) {
    int i = blockIdx.x * 256 + threadIdx.x;
    if (i < FLAT) flags[i] = 0;
}

__global__ __launch_bounds__(256) void scatter_flags_kernel(const int* __restrict__ ridx,
                                                            int n, int* __restrict__ flags) {
    int i = blockIdx.x * 256 + threadIdx.x;
    if (i < n) flags[ridx[i]] = 1;
}

// Pre-transpose weights to bf16: w1t[n][k] = W1[k][n] (256x256), w2t[n][k] = W2[k][n] (128x256)
__global__ __launch_bounds__(256) void prep_kernel(const float* __restrict__ W1,
                                                   const float* __restrict__ W2,
                                                   short* __restrict__ w1t,
                                                   short* __restrict__ w2t) {
    int i = blockIdx.x * 256 + threadIdx.x;
    if (i < 256 * 256) {
        int n = i >> 8, k = i & 255;
        w1t[i] = f2bf(W1[(size_t)k * 256 + n]);
    } else if (i < 256 * 256 + 128 * 256) {
        int j = i - 256 * 256;
        int n = j >> 8, k = j & 255;
        w2t[j] = f2bf(W2[(size_t)k * 128 + n]);
    }
}

// Streaming: id_embedding fp32 -> bf16 copy + fp32 norm table.
__global__ __launch_bounds__(256) void conv_kernel(const float* __restrict__ idemb,
                                                   short* __restrict__ idemb_bf,
                                                   float* __restrict__ norms) {
    const int sub = threadIdx.x & 31;
    const int g0 = (blockIdx.x * 256 + threadIdx.x) >> 5;
    const int ng = gridDim.x * 8;
    for (int row = g0; row < NID; row += ng) {
        float4 v = *(const float4*)(idemb + (size_t)row * DIM_E + sub * 4);
        float s = dot4(v, v);
#pragma unroll
        for (int off = 16; off >= 1; off >>= 1) s += __shfl_xor(s, off);
        bf16x4 p;
        p[0] = f2bf(v.x); p[1] = f2bf(v.y); p[2] = f2bf(v.z); p[3] = f2bf(v.w);
        *(bf16x4*)(idemb_bf + (size_t)row * DIM_E + sub * 4) = p;
        if (sub == 0) norms[row] = sqrtf(s);
    }
}

// Fused MLP via bf16 MFMA: feature = leaky(l2norm(v_feat) @ W1 + b1) @ W2 + b2
// 32 rows per block (LDS 32 KiB -> 5 blocks/CU), output bf16.
__global__ __launch_bounds__(256) void mlp_mfma_kernel(const float* __restrict__ vfeat,
                                                       const short* __restrict__ w1t,
                                                       const float* __restrict__ b1,
                                                       const short* __restrict__ w2t,
                                                       const float* __restrict__ b2,
                                                       short* __restrict__ featout) {
    // XOR-swizzled bf16 tiles: element (row, col) lives at row*256 + (col ^ ((row&7)<<3))
    __shared__ __align__(16) short As[32 * 256];
    __shared__ __align__(16) short Hs[32 * 256];
    const int t = threadIdx.x;
    const int w = t >> 6;       // wave 0..3
    const int l = t & 63;
    const int r0 = blockIdx.x * 32;
    const int fr = l & 15;      // fragment row/col index
    const int kg = l >> 4;      // k-group 0..3

    // ---- phase 1: issue all tile loads, then reduce norms, swizzled LDS write ----
    float4 v[8];
#pragma unroll
    for (int i = 0; i < 8; ++i) {
        int gr = r0 + i * 4 + w;
        v[i] = make_float4(0.f, 0.f, 0.f, 0.f);
        if (gr < NITEM) v[i] = *(const float4*)(vfeat + (size_t)gr * DIM_F + l * 4);
    }
#pragma unroll
    for (int i = 0; i < 8; ++i) {
        int row = i * 4 + w;
        float s = dot4(v[i], v[i]);
#pragma unroll
        for (int off = 32; off >= 1; off >>= 1) s += __shfl_xor(s, off);
        float inv = 1.f / fmaxf(sqrtf(s), 1e-12f);
        bf16x4 p;
        p[0] = f2bf(v[i].x * inv);
        p[1] = f2bf(v[i].y * inv);
        p[2] = f2bf(v[i].z * inv);
        p[3] = f2bf(v[i].w * inv);
        int sidx = row * 256 + ((l * 4) ^ ((row & 7) << 3));
        *(bf16x4*)(&As[sidx]) = p;
    }
    __syncthreads();

    // ---- stage 1: H = leaky(A @ W1T^T + b1), wave cols [w*64, w*64+64) ----
    {
        f32x4 acc[2][4];
#pragma unroll
        for (int rt = 0; rt < 2; ++rt)
#pragma unroll
            for (int ct = 0; ct < 4; ++ct) acc[rt][ct] = (f32x4){0.f, 0.f, 0.f, 0.f};

        float b1v[4];
#pragma unroll
        for (int ct = 0; ct < 4; ++ct) b1v[ct] = b1[w * 64 + ct * 16 + fr];

        for (int kc = 0; kc < 8; ++kc) {
            const int kb = kc * 32 + kg * 8;
            bf16x8 af[2];
#pragma unroll
            for (int rt = 0; rt < 2; ++rt) {
                int row = rt * 16 + fr;
                af[rt] = *(const bf16x8*)(&As[row * 256 + (kb ^ ((row & 7) << 3))]);
            }
#pragma unroll
            for (int ct = 0; ct < 4; ++ct) {
                int ncol = w * 64 + ct * 16 + fr;
                bf16x8 bfr = *(const bf16x8*)(w1t + (size_t)ncol * 256 + kb);
#pragma unroll
                for (int rt = 0; rt < 2; ++rt)
                    acc[rt][ct] = __builtin_amdgcn_mfma_f32_16x16x32_bf16(af[rt], bfr, acc[rt][ct], 0, 0, 0);
            }
        }
#pragma unroll
        for (int rt = 0; rt < 2; ++rt)
#pragma unroll
            for (int ct = 0; ct < 4; ++ct) {
                int colH = w * 64 + ct * 16 + fr;
#pragma unroll
                for (int r = 0; r < 4; ++r) {
                    float h = acc[rt][ct][r] + b1v[ct];
                    h = h > 0.f ? h : 0.01f * h;
                    int row = rt * 16 + kg * 4 + r;
                    Hs[row * 256 + (colH ^ ((row & 7) << 3))] = f2bf(h);
                }
            }
    }
    __syncthreads();

    // ---- stage 2: feature = H @ W2T^T + b2, wave cols [w*32, w*32+32) ----
    {
        f32x4 acc2[2][2];
#pragma unroll
        for (int rt = 0; rt < 2; ++rt)
#pragma unroll
            for (int ct = 0; ct < 2; ++ct) acc2[rt][ct] = (f32x4){0.f, 0.f, 0.f, 0.f};

        float b2v[2];
#pragma unroll
        for (int ct = 0; ct < 2; ++ct) b2v[ct] = b2[w * 32 + ct * 16 + fr];

        for (int kc = 0; kc < 8; ++kc) {
            const int kb = kc * 32 + kg * 8;
            bf16x8 hf[2];
#pragma unroll
            for (int rt = 0; rt < 2; ++rt) {
                int row = rt * 16 + fr;
                hf[rt] = *(const bf16x8*)(&Hs[row * 256 + (kb ^ ((row & 7) << 3))]);
            }
#pragma unroll
            for (int ct = 0; ct < 2; ++ct) {
                int ncol = w * 32 + ct * 16 + fr;
                bf16x8 bfr = *(const bf16x8*)(w2t + (size_t)ncol * 256 + kb);
#pragma unroll
                for (int rt = 0; rt < 2; ++rt)
                    acc2[rt][ct] = __builtin_amdgcn_mfma_f32_16x16x32_bf16(hf[rt], bfr, acc2[rt][ct], 0, 0, 0);
            }
        }
#pragma unroll
        for (int rt = 0; rt < 2; ++rt)
#pragma unroll
            for (int ct = 0; ct < 2; ++ct) {
                int col = w * 32 + ct * 16 + fr;
#pragma unroll
                for (int r = 0; r < 4; ++r) {
                    int row = r0 + rt * 16 + kg * 4 + r;
                    if (row < NITEM) featout[(size_t)row * DIM_E + col] = f2bf(acc2[rt][ct][r] + b2v[ct]);
                }
            }
    }
}

// One block per batch row (128 flat elements). 2 threads per element, bf16 gathers.
__global__ __launch_bounds__(256) void contrast_kernel(const int* __restrict__ user,
                                                       const int* __restrict__ item,
                                                       const int* __restrict__ flags,
                                                       const float* __restrict__ idemb,
                                                       const short* __restrict__ idemb_bf,
                                                       const float* __restrict__ norms,
                                                       const short* __restrict__ feat,
                                                       float* __restrict__ rowvals) {
    __shared__ float pe[128];           // normalized pos embedding (fp32)
    __shared__ float s1s[128], s2s[128], rs[128];
    const int row = blockIdx.x;
    const int t = threadIdx.x;

    if (t < 32) {
        int p = item[(size_t)row * NCOL];  // item_tensor[row][0]
        float4 v = *(const float4*)(idemb + (size_t)p * DIM_E + t * 4);
        float s = dot4(v, v);
#pragma unroll
        for (int off = 16; off >= 1; off >>= 1) s += __shfl_xor(s, off);
        float inv = 1.f / fmaxf(sqrtf(s), 1e-12f);
        *(float4*)(&pe[t * 4]) = make_float4(v.x * inv, v.y * inv, v.z * inv, v.w * inv);
    }
    __syncthreads();

    const int e = t >> 1;       // element 0..127
    const int h = t & 1;        // half of the 128-dim vector
    const size_t j = (size_t)row * NCOL + e;
    const int u = user[j];
    const int it = item[j];
    const int fl = flags[j];
    const short* up = idemb_bf + (size_t)u * DIM_E + h * 64;
    const short* ip = idemb_bf + (size_t)it * DIM_E + h * 64;
    const short* fp = feat + (size_t)(it - NUSER) * DIM_E + h * 64;

    bf16x8 ub[8], fb[8], xb[8];
#pragma unroll
    for (int i = 0; i < 8; ++i) { ub[i] = ((const bf16x8*)up)[i]; fb[i] = ((const bf16x8*)fp)[i]; }
    if (fl) {
#pragma unroll
        for (int i = 0; i < 8; ++i) xb[i] = fb[i];
    } else {
#pragma unroll
        for (int i = 0; i < 8; ++i) xb[i] = ((const bf16x8*)ip)[i];
    }
    float nu = norms[u];
    float ni = norms[it];

    float sf = 0.f, dpf = 0.f, dux = 0.f;
#pragma unroll
    for (int i = 0; i < 8; ++i) {
        float4 p0 = *(const float4*)(&pe[h * 64 + i * 8]);
        float4 p1 = *(const float4*)(&pe[h * 64 + i * 8 + 4]);
        float pk[8] = {p0.x, p0.y, p0.z, p0.w, p1.x, p1.y, p1.z, p1.w};
#pragma unroll
        for (int k = 0; k < 8; ++k) {
            float fv = bf2f(fb[i][k]);
            float uv = bf2f(ub[i][k]);
            float xv = bf2f(xb[i][k]);
            sf += fv * fv;
            dpf += pk[k] * fv;
            dux += uv * xv;
        }
    }
    sf += __shfl_xor(sf, 1);
    dpf += __shfl_xor(dpf, 1);
    dux += __shfl_xor(dux, 1);

    if (h == 0) {
        float fnorm = fmaxf(sqrtf(sf), 1e-12f);
        s1s[e] = expf(dpf / fnorm * 0.5f);      // / TEMP (=2)
        s2s[e] = expf(dux * 0.5f);
        rs[e] = nu + ni;
    }
    __syncthreads();

    if (t < 64) {
        float a1 = s1s[t] + s1s[t + 64];
        float a2 = s2s[t] + s2s[t + 64];
        float a3 = rs[t] + rs[t + 64];
#pragma unroll
        for (int off = 32; off >= 1; off >>= 1) {
            a1 += __shfl_xor(a1, off);
            a2 += __shfl_xor(a2, off);
            a3 += __shfl_xor(a3, off);
        }
        if (t == 0) {
            rowvals[row * 4 + 0] = logf(a1) - logf(s1s[0]);
            rowvals[row * 4 + 1] = logf(a2) - logf(s2s[0]);
            rowvals[row * 4 + 2] = a3;
        }
    }
}

__global__ __launch_bounds__(256) void finalize_kernel(const float* __restrict__ rowvals,
                                                       float* __restrict__ out) {
    float c1 = 0.f, c2 = 0.f, rg = 0.f;
    for (int i = threadIdx.x; i < BATCH; i += 256) {
        c1 += rowvals[i * 4 + 0];
        c2 += rowvals[i * 4 + 1];
        rg += rowvals[i * 4 + 2];
    }
#pragma unroll
    for (int off = 32; off >= 1; off >>= 1) {
        c1 += __shfl_xor(c1, off);
        c2 += __shfl_xor(c2, off);
        rg += __shfl_xor(rg, off);
    }
    __shared__ float buf[4][3];
    int wid = threadIdx.x >> 6, lane = threadIdx.x & 63;
    if (lane == 0) { buf[wid][0] = c1; buf[wid][1] = c2; buf[wid][2] = rg; }
    __syncthreads();
    if (threadIdx.x == 0) {
        float C1 = buf[0][0] + buf[1][0] + buf[2][0] + buf[3][0];
        float C2 = buf[0][1] + buf[1][1] + buf[2][1] + buf[3][1];
        float R  = buf[0][2] + buf[1][2] + buf[2][2] + buf[3][2];
        out[0] = 0.5f * (C1 / (float)BATCH) + 0.5f * (C2 / (float)BATCH);
        out[1] = 0.5f * (R / (float)FLAT);
    }
}

extern "C" void kernel_launch(void* const* d_in, const int* in_sizes, int n_in,
                              void* d_out, int out_size, void* d_ws, size_t ws_size,
                              hipStream_t stream) {
    const int* user = (const int*)d_in[0];
    const int* item = (const int*)d_in[1];
    const int* ridx = (const int*)d_in[2];
    const float* idemb = (const float*)d_in[3];
    const float* vfeat = (const float*)d_in[4];
    const float* W1 = (const float*)d_in[5];
    const float* b1 = (const float*)d_in[6];
    const float* W2 = (const float*)d_in[7];
    const float* b2 = (const float*)d_in[8];
    float* out = (float*)d_out;

    char* ws = (char*)d_ws;
    short* feat_bf  = (short*)(ws);                     // 12,800,000 B
    short* idemb_bf = (short*)(ws + 12800000);          // 38,400,000 B
    float* norms    = (float*)(ws + 51200000);          //    600,000 B
    int*   flags    = (int*)  (ws + 51800000);          //    524,288 B
    float* rowvals  = (float*)(ws + 52324288);          //     16,384 B
    short* w1t      = (short*)(ws + 52340672);          //    131,072 B
    short* w2t      = (short*)(ws + 52471744);          //     65,536 B  (end: 52,537,280)

    const int nridx = in_sizes[2];

    conv_kernel<<<dim3(2048), dim3(256), 0, stream>>>(idemb, idemb_bf, norms);
    prep_kernel<<<dim3(384), dim3(256), 0, stream>>>(W1, W2, w1t, w2t);
    zero_flags_kernel<<<dim3((FLAT + 255) / 256), dim3(256), 0, stream>>>(flags);
    scatter_flags_kernel<<<dim3((nridx + 255) / 256), dim3(256), 0, stream>>>(ridx, nridx, flags);
    mlp_mfma_kernel<<<dim3((NITEM + 31) / 32), dim3(256), 0, stream>>>(vfeat, w1t, b1, w2t, b2, feat_bf);
    contrast_kernel<<<dim3(BATCH), dim3(256), 0, stream>>>(user, item, flags, idemb, idemb_bf, norms, feat_bf, rowvals);
    finalize_kernel<<<dim3(1), dim3(256), 0, stream>>>(rowvals, out);
}

// Round 5
// 79.055 us; speedup vs baseline: 1.2907x; 1.2907x over previous
//
#include <hip/hip_runtime.h>
#include <math.h>

#define NUSER 100000
#define NITEM 50000
#define NID   (NUSER + NITEM)
#define DIM_E 128
#define DIM_F 256
#define BATCH 1024
#define NCOL 128            /* 1 + NUM_NEG */
#define FLAT (BATCH * NCOL)

typedef __attribute__((ext_vector_type(8))) short bf16x8;
typedef __attribute__((ext_vector_type(4))) short bf16x4;
typedef __attribute__((ext_vector_type(4))) float f32x4;

__device__ __forceinline__ float dot4(float4 a, float4 b) {
    return a.x * b.x + a.y * b.y + a.z * b.z + a.w * b.w;
}

__device__ __forceinline__ short f2bf(float x) {
    unsigned u = __float_as_uint(x);
    unsigned r = (u + 0x7FFFu + ((u >> 16) & 1u)) >> 16;
    return (short)r;
}

__device__ __forceinline__ float bf2f(short s) {
    return __uint_as_float(((unsigned)(unsigned short)s) << 16);
}

__global__ __launch_bounds__(256) void zero_flags_kernel(int* __restrict__ flags) {
    int i = blockIdx.x * 256 + threadIdx.x;
    if (i < FLAT) flags[i] = 0;
}

__global__ __launch_bounds__(256) void scatter_flags_kernel(const int* __restrict__ ridx,
                                                            int n, int* __restrict__ flags) {
    int i = blockIdx.x * 256 + threadIdx.x;
    if (i < n) flags[ridx[i]] = 1;
}

// Pre-transpose weights to bf16: w1t[n][k] = W1[k][n] (256x256), w2t[n][k] = W2[k][n] (128x256)
__global__ __launch_bounds__(256) void prep_kernel(const float* __restrict__ W1,
                                                   const float* __restrict__ W2,
                                                   short* __restrict__ w1t,
                                                   short* __restrict__ w2t) {
    int i = blockIdx.x * 256 + threadIdx.x;
    if (i < 256 * 256) {
        int n = i >> 8, k = i & 255;
        w1t[i] = f2bf(W1[(size_t)k * 256 + n]);
    } else if (i < 256 * 256 + 128 * 256) {
        int j = i - 256 * 256;
        int n = j >> 8, k = j & 255;
        w2t[j] = f2bf(W2[(size_t)k * 128 + n]);
    }
}

// Streaming: id_embedding fp32 -> bf16 copy + fp32 norm table.
__global__ __launch_bounds__(256) void conv_kernel(const float* __restrict__ idemb,
                                                   short* __restrict__ idemb_bf,
                                                   float* __restrict__ norms) {
    const int sub = threadIdx.x & 31;
    const int g0 = (blockIdx.x * 256 + threadIdx.x) >> 5;
    const int ng = gridDim.x * 8;
    for (int row = g0; row < NID; row += ng) {
        float4 v = *(const float4*)(idemb + (size_t)row * DIM_E + sub * 4);
        float s = dot4(v, v);
#pragma unroll
        for (int off = 16; off >= 1; off >>= 1) s += __shfl_xor(s, off);
        bf16x4 p;
        p[0] = f2bf(v.x); p[1] = f2bf(v.y); p[2] = f2bf(v.z); p[3] = f2bf(v.w);
        *(bf16x4*)(idemb_bf + (size_t)row * DIM_E + sub * 4) = p;
        if (sub == 0) norms[row] = sqrtf(s);
    }
}

// Normalize 16 fp32 (one row-slice), write to swizzled LDS tile as bf16.
// srow in [0,32), q in [0,16): cols q*16..q*16+15.
__device__ __forceinline__ void stage_rows(const float4 va[4], int srow, int q,
                                           short* __restrict__ As) {
    float s = 0.f;
#pragma unroll
    for (int c = 0; c < 4; ++c) s += dot4(va[c], va[c]);
#pragma unroll
    for (int off = 8; off >= 1; off >>= 1) s += __shfl_xor(s, off);
    float inv = 1.f / fmaxf(sqrtf(s), 1e-12f);
    bf16x8 p0, p1;
    p0[0] = f2bf(va[0].x * inv); p0[1] = f2bf(va[0].y * inv);
    p0[2] = f2bf(va[0].z * inv); p0[3] = f2bf(va[0].w * inv);
    p0[4] = f2bf(va[1].x * inv); p0[5] = f2bf(va[1].y * inv);
    p0[6] = f2bf(va[1].z * inv); p0[7] = f2bf(va[1].w * inv);
    p1[0] = f2bf(va[2].x * inv); p1[1] = f2bf(va[2].y * inv);
    p1[2] = f2bf(va[2].z * inv); p1[3] = f2bf(va[2].w * inv);
    p1[4] = f2bf(va[3].x * inv); p1[5] = f2bf(va[3].y * inv);
    p1[6] = f2bf(va[3].z * inv); p1[7] = f2bf(va[3].w * inv);
    const int sw = (srow & 7) << 3;
    *(bf16x8*)(&As[srow * 256 + ((q * 16) ^ sw)]) = p0;
    *(bf16x8*)(&As[srow * 256 + ((q * 16 + 8) ^ sw)]) = p1;
}

// Weights-stationary fused MLP: feature = leaky(l2norm(v_feat) @ W1 + b1) @ W2 + b2
// 512 threads (8 waves). Each wave keeps its W1 (32-col) and W2 (16-col) panels in
// registers; block grid-strides over 32-row tiles with register prefetch of next tile.
__global__ __launch_bounds__(512, 2) void mlp_mfma_kernel(const float* __restrict__ vfeat,
                                                          const short* __restrict__ w1t,
                                                          const float* __restrict__ b1,
                                                          const short* __restrict__ w2t,
                                                          const float* __restrict__ b2,
                                                          short* __restrict__ featout) {
    // XOR-swizzled bf16 tiles: element (row, col) lives at row*256 + (col ^ ((row&7)<<3))
    __shared__ __align__(16) short As[32 * 256];
    __shared__ __align__(16) short Hs[32 * 256];
    const int t = threadIdx.x;
    const int w = t >> 6;       // wave 0..7
    const int l = t & 63;
    const int fr = l & 15;      // fragment row/col index
    const int kg = l >> 4;      // k-group 0..3
    const int srow = t >> 4;    // staging row 0..31
    const int q = t & 15;       // staging col-quarter
    const int NT = (NITEM + 31) / 32;

    // ---- load weight panels into registers (once per block) ----
    bf16x8 B1f[8][2];
    bf16x8 B2f[8];
#pragma unroll
    for (int kc = 0; kc < 8; ++kc) {
#pragma unroll
        for (int ct = 0; ct < 2; ++ct)
            B1f[kc][ct] = *(const bf16x8*)(w1t + (size_t)(w * 32 + ct * 16 + fr) * 256 + kc * 32 + kg * 8);
        B2f[kc] = *(const bf16x8*)(w2t + (size_t)(w * 16 + fr) * 256 + kc * 32 + kg * 8);
    }
    float b1v[2];
    b1v[0] = b1[w * 32 + fr];
    b1v[1] = b1[w * 32 + 16 + fr];
    const float b2v = b2[w * 16 + fr];

    // ---- prologue: stage tile-0 ----
    int tile = blockIdx.x;
    {
        float4 va[4];
        int gr = tile * 32 + srow;
        const float* src = vfeat + (size_t)gr * DIM_F + q * 16;
#pragma unroll
        for (int c = 0; c < 4; ++c)
            va[c] = (gr < NITEM) ? *(const float4*)(src + c * 4) : make_float4(0.f, 0.f, 0.f, 0.f);
        stage_rows(va, srow, q, As);
    }
    __syncthreads();

    while (tile < NT) {
        const int tnext = tile + gridDim.x;
        // ---- issue next tile's loads early (hide HBM under compute) ----
        float4 vb[4];
        if (tnext < NT) {
            int gr = tnext * 32 + srow;
            const float* src = vfeat + (size_t)gr * DIM_F + q * 16;
#pragma unroll
            for (int c = 0; c < 4; ++c)
                vb[c] = (gr < NITEM) ? *(const float4*)(src + c * 4) : make_float4(0.f, 0.f, 0.f, 0.f);
        }

        // ---- stage 1: H = leaky(A @ W1 + b1), wave cols [w*32, w*32+32) ----
        {
            f32x4 acc1[2][2];
#pragma unroll
            for (int rt = 0; rt < 2; ++rt)
#pragma unroll
                for (int ct = 0; ct < 2; ++ct) acc1[rt][ct] = (f32x4){0.f, 0.f, 0.f, 0.f};
#pragma unroll
            for (int kc = 0; kc < 8; ++kc) {
                const int kb = kc * 32 + kg * 8;
                bf16x8 af[2];
#pragma unroll
                for (int rt = 0; rt < 2; ++rt) {
                    int row = rt * 16 + fr;
                    af[rt] = *(const bf16x8*)(&As[row * 256 + (kb ^ ((row & 7) << 3))]);
                }
#pragma unroll
                for (int ct = 0; ct < 2; ++ct)
#pragma unroll
                    for (int rt = 0; rt < 2; ++rt)
                        acc1[rt][ct] = __builtin_amdgcn_mfma_f32_16x16x32_bf16(af[rt], B1f[kc][ct], acc1[rt][ct], 0, 0, 0);
            }
#pragma unroll
            for (int rt = 0; rt < 2; ++rt)
#pragma unroll
                for (int ct = 0; ct < 2; ++ct) {
                    int colH = w * 32 + ct * 16 + fr;
#pragma unroll
                    for (int r = 0; r < 4; ++r) {
                        float h = acc1[rt][ct][r] + b1v[ct];
                        h = h > 0.f ? h : 0.01f * h;
                        int row = rt * 16 + kg * 4 + r;
                        Hs[row * 256 + (colH ^ ((row & 7) << 3))] = f2bf(h);
                    }
                }
        }
        __syncthreads();

        // ---- stage 2: feature = H @ W2 + b2, wave cols [w*16, w*16+16) ----
        {
            f32x4 acc2[2];
            acc2[0] = (f32x4){0.f, 0.f, 0.f, 0.f};
            acc2[1] = (f32x4){0.f, 0.f, 0.f, 0.f};
#pragma unroll
            for (int kc = 0; kc < 8; ++kc) {
                const int kb = kc * 32 + kg * 8;
#pragma unroll
                for (int rt = 0; rt < 2; ++rt) {
                    int row = rt * 16 + fr;
                    bf16x8 hf = *(const bf16x8*)(&Hs[row * 256 + (kb ^ ((row & 7) << 3))]);
                    acc2[rt] = __builtin_amdgcn_mfma_f32_16x16x32_bf16(hf, B2f[kc], acc2[rt], 0, 0, 0);
                }
            }
            const int col = w * 16 + fr;
#pragma unroll
            for (int rt = 0; rt < 2; ++rt)
#pragma unroll
                for (int r = 0; r < 4; ++r) {
                    int row = tile * 32 + rt * 16 + kg * 4 + r;
                    if (row < NITEM) featout[(size_t)row * DIM_E + col] = f2bf(acc2[rt][r] + b2v);
                }
        }

        // ---- stage next tile's A (loads already in flight) ----
        if (tnext < NT) stage_rows(vb, srow, q, As);
        __syncthreads();
        tile = tnext;
    }
}

// One block per batch row (128 flat elements). 2 threads per element, bf16 gathers.
__global__ __launch_bounds__(256) void contrast_kernel(const int* __restrict__ user,
                                                       const int* __restrict__ item,
                                                       const int* __restrict__ flags,
                                                       const float* __restrict__ idemb,
                                                       const short* __restrict__ idemb_bf,
                                                       const float* __restrict__ norms,
                                                       const short* __restrict__ feat,
                                                       float* __restrict__ rowvals) {
    __shared__ float pe[128];           // normalized pos embedding (fp32)
    __shared__ float s1s[128], s2s[128], rs[128];
    const int row = blockIdx.x;
    const int t = threadIdx.x;

    if (t < 32) {
        int p = item[(size_t)row * NCOL];  // item_tensor[row][0]
        float4 v = *(const float4*)(idemb + (size_t)p * DIM_E + t * 4);
        float s = dot4(v, v);
#pragma unroll
        for (int off = 16; off >= 1; off >>= 1) s += __shfl_xor(s, off);
        float inv = 1.f / fmaxf(sqrtf(s), 1e-12f);
        *(float4*)(&pe[t * 4]) = make_float4(v.x * inv, v.y * inv, v.z * inv, v.w * inv);
    }
    __syncthreads();

    const int e = t >> 1;       // element 0..127
    const int h = t & 1;        // half of the 128-dim vector
    const size_t j = (size_t)row * NCOL + e;
    const int u = user[j];
    const int it = item[j];
    const int fl = flags[j];
    const short* up = idemb_bf + (size_t)u * DIM_E + h * 64;
    const short* ip = idemb_bf + (size_t)it * DIM_E + h * 64;
    const short* fp = feat + (size_t)(it - NUSER) * DIM_E + h * 64;

    bf16x8 ub[8], fb[8], xb[8];
#pragma unroll
    for (int i = 0; i < 8; ++i) { ub[i] = ((const bf16x8*)up)[i]; fb[i] = ((const bf16x8*)fp)[i]; }
    if (fl) {
#pragma unroll
        for (int i = 0; i < 8; ++i) xb[i] = fb[i];
    } else {
#pragma unroll
        for (int i = 0; i < 8; ++i) xb[i] = ((const bf16x8*)ip)[i];
    }
    float nu = norms[u];
    float ni = norms[it];

    float sf = 0.f, dpf = 0.f, dux = 0.f;
#pragma unroll
    for (int i = 0; i < 8; ++i) {
        float4 p0 = *(const float4*)(&pe[h * 64 + i * 8]);
        float4 p1 = *(const float4*)(&pe[h * 64 + i * 8 + 4]);
        float pk[8] = {p0.x, p0.y, p0.z, p0.w, p1.x, p1.y, p1.z, p1.w};
#pragma unroll
        for (int k = 0; k < 8; ++k) {
            float fv = bf2f(fb[i][k]);
            float uv = bf2f(ub[i][k]);
            float xv = bf2f(xb[i][k]);
            sf += fv * fv;
            dpf += pk[k] * fv;
            dux += uv * xv;
        }
    }
    sf += __shfl_xor(sf, 1);
    dpf += __shfl_xor(dpf, 1);
    dux += __shfl_xor(dux, 1);

    if (h == 0) {
        float fnorm = fmaxf(sqrtf(sf), 1e-12f);
        s1s[e] = expf(dpf / fnorm * 0.5f);      // / TEMP (=2)
        s2s[e] = expf(dux * 0.5f);
        rs[e] = nu + ni;
    }
    __syncthreads();

    if (t < 64) {
        float a1 = s1s[t] + s1s[t + 64];
        float a2 = s2s[t] + s2s[t + 64];
        float a3 = rs[t] + rs[t + 64];
#pragma unroll
        for (int off = 32; off >= 1; off >>= 1) {
            a1 += __shfl_xor(a1, off);
            a2 += __shfl_xor(a2, off);
            a3 += __shfl_xor(a3, off);
        }
        if (t == 0) {
            rowvals[row * 4 + 0] = logf(a1) - logf(s1s[0]);
            rowvals[row * 4 + 1] = logf(a2) - logf(s2s[0]);
            rowvals[row * 4 + 2] = a3;
        }
    }
}

__global__ __launch_bounds__(256) void finalize_kernel(const float* __restrict__ rowvals,
                                                       float* __restrict__ out) {
    float c1 = 0.f, c2 = 0.f, rg = 0.f;
    for (int i = threadIdx.x; i < BATCH; i += 256) {
        c1 += rowvals[i * 4 + 0];
        c2 += rowvals[i * 4 + 1];
        rg += rowvals[i * 4 + 2];
    }
#pragma unroll
    for (int off = 32; off >= 1; off >>= 1) {
        c1 += __shfl_xor(c1, off);
        c2 += __shfl_xor(c2, off);
        rg += __shfl_xor(rg, off);
    }
    __shared__ float buf[4][3];
    int wid = threadIdx.x >> 6, lane = threadIdx.x & 63;
    if (lane == 0) { buf[wid][0] = c1; buf[wid][1] = c2; buf[wid][2] = rg; }
    __syncthreads();
    if (threadIdx.x == 0) {
        float C1 = buf[0][0] + buf[1][0] + buf[2][0] + buf[3][0];
        float C2 = buf[0][1] + buf[1][1] + buf[2][1] + buf[3][1];
        float R  = buf[0][2] + buf[1][2] + buf[2][2] + buf[3][2];
        out[0] = 0.5f * (C1 / (float)BATCH) + 0.5f * (C2 / (float)BATCH);
        out[1] = 0.5f * (R / (float)FLAT);
    }
}

extern "C" void kernel_launch(void* const* d_in, const int* in_sizes, int n_in,
                              void* d_out, int out_size, void* d_ws, size_t ws_size,
                              hipStream_t stream) {
    const int* user = (const int*)d_in[0];
    const int* item = (const int*)d_in[1];
    const int* ridx = (const int*)d_in[2];
    const float* idemb = (const float*)d_in[3];
    const float* vfeat = (const float*)d_in[4];
    const float* W1 = (const float*)d_in[5];
    const float* b1 = (const float*)d_in[6];
    const float* W2 = (const float*)d_in[7];
    const float* b2 = (const float*)d_in[8];
    float* out = (float*)d_out;

    char* ws = (char*)d_ws;
    short* feat_bf  = (short*)(ws);                     // 12,800,000 B
    short* idemb_bf = (short*)(ws + 12800000);          // 38,400,000 B
    float* norms    = (float*)(ws + 51200000);          //    600,000 B
    int*   flags    = (int*)  (ws + 51800000);          //    524,288 B
    float* rowvals  = (float*)(ws + 52324288);          //     16,384 B
    short* w1t      = (short*)(ws + 52340672);          //    131,072 B
    short* w2t      = (short*)(ws + 52471744);          //     65,536 B  (end: 52,537,280)

    const int nridx = in_sizes[2];

    conv_kernel<<<dim3(2048), dim3(256), 0, stream>>>(idemb, idemb_bf, norms);
    prep_kernel<<<dim3(384), dim3(256), 0, stream>>>(W1, W2, w1t, w2t);
    zero_flags_kernel<<<dim3((FLAT + 255) / 256), dim3(256), 0, stream>>>(flags);
    scatter_flags_kernel<<<dim3((nridx + 255) / 256), dim3(256), 0, stream>>>(ridx, nridx, flags);
    mlp_mfma_kernel<<<dim3(256), dim3(512), 0, stream>>>(vfeat, w1t, b1, w2t, b2, feat_bf);
    contrast_kernel<<<dim3(BATCH), dim3(256), 0, stream>>>(user, item, flags, idemb, idemb_bf, norms, feat_bf, rowvals);
    finalize_kernel<<<dim3(1), dim3(256), 0, stream>>>(rowvals, out);
}

// Round 7
// 77.970 us; speedup vs baseline: 1.3086x; 1.0139x over previous
//
#include <hip/hip_runtime.h>
#include <math.h>

#define NUSER 100000
#define NITEM 50000
#define NID   (NUSER + NITEM)
#define DIM_E 128
#define DIM_F 256
#define BATCH 1024
#define NCOL 128            /* 1 + NUM_NEG */
#define FLAT (BATCH * NCOL)

typedef __attribute__((ext_vector_type(8))) short bf16x8;
typedef __attribute__((ext_vector_type(4))) short bf16x4;
typedef __attribute__((ext_vector_type(4))) float f32x4;

__device__ __forceinline__ float dot4(float4 a, float4 b) {
    return a.x * b.x + a.y * b.y + a.z * b.z + a.w * b.w;
}

__device__ __forceinline__ short f2bf(float x) {
    unsigned u = __float_as_uint(x);
    unsigned r = (u + 0x7FFFu + ((u >> 16) & 1u)) >> 16;
    return (short)r;
}

__device__ __forceinline__ float bf2f(short s) {
    return __uint_as_float(((unsigned)(unsigned short)s) << 16);
}

// Kernel 1: bf16 weight transposes + zero flags. Grid 512 x 256.
__global__ __launch_bounds__(256) void prep0_kernel(const float* __restrict__ W1,
                                                    const float* __restrict__ W2,
                                                    short* __restrict__ w1t,
                                                    short* __restrict__ w2t,
                                                    int* __restrict__ flags) {
    int i = blockIdx.x * 256 + threadIdx.x;
    if (i < FLAT) flags[i] = 0;
    if (i < 256 * 256) {
        int n = i >> 8, k = i & 255;
        w1t[i] = f2bf(W1[(size_t)k * 256 + n]);
    } else if (i < 256 * 256 + 128 * 256) {
        int j = i - 256 * 256;
        int n = j >> 8, k = j & 255;
        w2t[j] = f2bf(W2[(size_t)k * 128 + n]);
    }
}

// Normalize 16 fp32 (one row-slice), write to swizzled LDS tile as bf16.
__device__ __forceinline__ void stage_rows(const float4 va[4], int srow, int q,
                                           short* __restrict__ As) {
    float s = 0.f;
#pragma unroll
    for (int c = 0; c < 4; ++c) s += dot4(va[c], va[c]);
#pragma unroll
    for (int off = 8; off >= 1; off >>= 1) s += __shfl_xor(s, off);
    float inv = 1.f / fmaxf(sqrtf(s), 1e-12f);
    bf16x8 p0, p1;
    p0[0] = f2bf(va[0].x * inv); p0[1] = f2bf(va[0].y * inv);
    p0[2] = f2bf(va[0].z * inv); p0[3] = f2bf(va[0].w * inv);
    p0[4] = f2bf(va[1].x * inv); p0[5] = f2bf(va[1].y * inv);
    p0[6] = f2bf(va[1].z * inv); p0[7] = f2bf(va[1].w * inv);
    p1[0] = f2bf(va[2].x * inv); p1[1] = f2bf(va[2].y * inv);
    p1[2] = f2bf(va[2].z * inv); p1[3] = f2bf(va[2].w * inv);
    p1[4] = f2bf(va[3].x * inv); p1[5] = f2bf(va[3].y * inv);
    p1[6] = f2bf(va[3].z * inv); p1[7] = f2bf(va[3].w * inv);
    const int sw = (srow & 7) << 3;
    *(bf16x8*)(&As[srow * 256 + ((q * 16) ^ sw)]) = p0;
    *(bf16x8*)(&As[srow * 256 + ((q * 16 + 8) ^ sw)]) = p1;
}

// Kernel 2 (fused): blocks 0..255 = weights-stationary MLP; blocks 256..1023 =
// id_embedding bf16 conversion + norms (grid-stride) and ridx flag-scatter.
__global__ __launch_bounds__(512, 2) void fused_prep_kernel(const float* __restrict__ vfeat,
                                                            const short* __restrict__ w1t,
                                                            const float* __restrict__ b1,
                                                            const short* __restrict__ w2t,
                                                            const float* __restrict__ b2,
                                                            short* __restrict__ featout,
                                                            const float* __restrict__ idemb,
                                                            short* __restrict__ idemb_bf,
                                                            float* __restrict__ norms,
                                                            const int* __restrict__ ridx,
                                                            int nridx,
                                                            int* __restrict__ flags) {
    __shared__ __align__(16) short As[32 * 256];
    __shared__ __align__(16) short Hs[32 * 256];
    const int t = threadIdx.x;

    if (blockIdx.x >= 256) {
        // ---------------- conv + scatter role ----------------
        const int blk = blockIdx.x - 256;       // 0..767
        if (blk < 128) {
            for (int i = blk * 512 + t; i < nridx; i += 128 * 512) flags[ridx[i]] = 1;
        }
        const int sub = t & 31;
        int row = blk * 16 + (t >> 5);
        for (; row < NID; row += 768 * 16) {
            float4 v = *(const float4*)(idemb + (size_t)row * DIM_E + sub * 4);
            float s = dot4(v, v);
#pragma unroll
            for (int off = 16; off >= 1; off >>= 1) s += __shfl_xor(s, off);
            bf16x4 p;
            p[0] = f2bf(v.x); p[1] = f2bf(v.y); p[2] = f2bf(v.z); p[3] = f2bf(v.w);
            *(bf16x4*)(idemb_bf + (size_t)row * DIM_E + sub * 4) = p;
            if (sub == 0) norms[row] = sqrtf(s);
        }
        return;
    }

    // ---------------- MLP role (blocks 0..255) ----------------
    const int w = t >> 6;       // wave 0..7
    const int l = t & 63;
    const int fr = l & 15;
    const int kg = l >> 4;
    const int srow = t >> 4;
    const int q = t & 15;
    const int NT = (NITEM + 31) / 32;

    bf16x8 B1f[8][2];
    bf16x8 B2f[8];
#pragma unroll
    for (int kc = 0; kc < 8; ++kc) {
#pragma unroll
        for (int ct = 0; ct < 2; ++ct)
            B1f[kc][ct] = *(const bf16x8*)(w1t + (size_t)(w * 32 + ct * 16 + fr) * 256 + kc * 32 + kg * 8);
        B2f[kc] = *(const bf16x8*)(w2t + (size_t)(w * 16 + fr) * 256 + kc * 32 + kg * 8);
    }
    float b1v[2];
    b1v[0] = b1[w * 32 + fr];
    b1v[1] = b1[w * 32 + 16 + fr];
    const float b2v = b2[w * 16 + fr];

    int tile = blockIdx.x;
    {
        float4 va[4];
        int gr = tile * 32 + srow;
        const float* src = vfeat + (size_t)gr * DIM_F + q * 16;
#pragma unroll
        for (int c = 0; c < 4; ++c)
            va[c] = (gr < NITEM) ? *(const float4*)(src + c * 4) : make_float4(0.f, 0.f, 0.f, 0.f);
        stage_rows(va, srow, q, As);
    }
    __syncthreads();

    while (tile < NT) {
        const int tnext = tile + 256;
        float4 vb[4];
        if (tnext < NT) {
            int gr = tnext * 32 + srow;
            const float* src = vfeat + (size_t)gr * DIM_F + q * 16;
#pragma unroll
            for (int c = 0; c < 4; ++c)
                vb[c] = (gr < NITEM) ? *(const float4*)(src + c * 4) : make_float4(0.f, 0.f, 0.f, 0.f);
        }

        // stage 1
        {
            f32x4 acc1[2][2];
#pragma unroll
            for (int rt = 0; rt < 2; ++rt)
#pragma unroll
                for (int ct = 0; ct < 2; ++ct) acc1[rt][ct] = (f32x4){0.f, 0.f, 0.f, 0.f};
#pragma unroll
            for (int kc = 0; kc < 8; ++kc) {
                const int kb = kc * 32 + kg * 8;
                bf16x8 af[2];
#pragma unroll
                for (int rt = 0; rt < 2; ++rt) {
                    int row = rt * 16 + fr;
                    af[rt] = *(const bf16x8*)(&As[row * 256 + (kb ^ ((row & 7) << 3))]);
                }
#pragma unroll
                for (int ct = 0; ct < 2; ++ct)
#pragma unroll
                    for (int rt = 0; rt < 2; ++rt)
                        acc1[rt][ct] = __builtin_amdgcn_mfma_f32_16x16x32_bf16(af[rt], B1f[kc][ct], acc1[rt][ct], 0, 0, 0);
            }
#pragma unroll
            for (int rt = 0; rt < 2; ++rt)
#pragma unroll
                for (int ct = 0; ct < 2; ++ct) {
                    int colH = w * 32 + ct * 16 + fr;
#pragma unroll
                    for (int r = 0; r < 4; ++r) {
                        float h = acc1[rt][ct][r] + b1v[ct];
                        h = h > 0.f ? h : 0.01f * h;
                        int row = rt * 16 + kg * 4 + r;
                        Hs[row * 256 + (colH ^ ((row & 7) << 3))] = f2bf(h);
                    }
                }
        }
        __syncthreads();

        // stage 2
        {
            f32x4 acc2[2];
            acc2[0] = (f32x4){0.f, 0.f, 0.f, 0.f};
            acc2[1] = (f32x4){0.f, 0.f, 0.f, 0.f};
#pragma unroll
            for (int kc = 0; kc < 8; ++kc) {
                const int kb = kc * 32 + kg * 8;
#pragma unroll
                for (int rt = 0; rt < 2; ++rt) {
                    int row = rt * 16 + fr;
                    bf16x8 hf = *(const bf16x8*)(&Hs[row * 256 + (kb ^ ((row & 7) << 3))]);
                    acc2[rt] = __builtin_amdgcn_mfma_f32_16x16x32_bf16(hf, B2f[kc], acc2[rt], 0, 0, 0);
                }
            }
            const int col = w * 16 + fr;
#pragma unroll
            for (int rt = 0; rt < 2; ++rt)
#pragma unroll
                for (int r = 0; r < 4; ++r) {
                    int row = tile * 32 + rt * 16 + kg * 4 + r;
                    if (row < NITEM) featout[(size_t)row * DIM_E + col] = f2bf(acc2[rt][r] + b2v);
                }
        }

        if (tnext < NT) stage_rows(vb, srow, q, As);
        __syncthreads();
        tile = tnext;
    }
}

// Kernel 3: contrast. 2 blocks per batch row, 64 elements each, 2 threads/element,
// 128 threads per block. Writes partial sums; part 0 also writes raw positive logits.
__global__ __launch_bounds__(128) void contrast_kernel(const int* __restrict__ user,
                                                       const int* __restrict__ item,
                                                       const int* __restrict__ flags,
                                                       const float* __restrict__ idemb,
                                                       const short* __restrict__ idemb_bf,
                                                       const float* __restrict__ norms,
                                                       const short* __restrict__ feat,
                                                       float* __restrict__ rowpart) {
    __shared__ float pe[128];           // normalized pos embedding (fp32)
    __shared__ float s1s[64], s2s[64], rs[64];
    __shared__ float dpos[2];
    const int row = blockIdx.x >> 1;
    const int part = blockIdx.x & 1;
    const int t = threadIdx.x;          // 0..127

    if (t < 32) {
        int p = item[(size_t)row * NCOL];  // item_tensor[row][0]
        float4 v = *(const float4*)(idemb + (size_t)p * DIM_E + t * 4);
        float s = dot4(v, v);
#pragma unroll
        for (int off = 16; off >= 1; off >>= 1) s += __shfl_xor(s, off);
        float inv = 1.f / fmaxf(sqrtf(s), 1e-12f);
        *(float4*)(&pe[t * 4]) = make_float4(v.x * inv, v.y * inv, v.z * inv, v.w * inv);
    }
    __syncthreads();

    const int el = t >> 1;      // local element 0..63
    const int e = part * 64 + el;
    const int h = t & 1;        // half of the 128-dim vector
    const size_t j = (size_t)row * NCOL + e;
    const int u = user[j];
    const int it = item[j];
    const int fl = flags[j];
    const short* up = idemb_bf + (size_t)u * DIM_E + h * 64;
    const short* ip = idemb_bf + (size_t)it * DIM_E + h * 64;
    const short* fp = feat + (size_t)(it - NUSER) * DIM_E + h * 64;

    bf16x8 ub[8], fb[8], xb[8];
#pragma unroll
    for (int i = 0; i < 8; ++i) { ub[i] = ((const bf16x8*)up)[i]; fb[i] = ((const bf16x8*)fp)[i]; }
    if (fl) {
#pragma unroll
        for (int i = 0; i < 8; ++i) xb[i] = fb[i];
    } else {
#pragma unroll
        for (int i = 0; i < 8; ++i) xb[i] = ((const bf16x8*)ip)[i];
    }
    float nu = norms[u];
    float ni = norms[it];

    float sf = 0.f, dpf = 0.f, dux = 0.f;
#pragma unroll
    for (int i = 0; i < 8; ++i) {
        float4 p0 = *(const float4*)(&pe[h * 64 + i * 8]);
        float4 p1 = *(const float4*)(&pe[h * 64 + i * 8 + 4]);
        float pk[8] = {p0.x, p0.y, p0.z, p0.w, p1.x, p1.y, p1.z, p1.w};
#pragma unroll
        for (int k = 0; k < 8; ++k) {
            float fv = bf2f(fb[i][k]);
            float uv = bf2f(ub[i][k]);
            float xv = bf2f(xb[i][k]);
            sf += fv * fv;
            dpf += pk[k] * fv;
            dux += uv * xv;
        }
    }
    sf += __shfl_xor(sf, 1);
    dpf += __shfl_xor(dpf, 1);
    dux += __shfl_xor(dux, 1);

    if (h == 0) {
        float fnorm = fmaxf(sqrtf(sf), 1e-12f);
        float d1 = dpf / fnorm * 0.5f;          // / TEMP (=2)
        float d2 = dux * 0.5f;
        s1s[el] = expf(d1);
        s2s[el] = expf(d2);
        rs[el] = nu + ni;
        if (e == 0) { dpos[0] = d1; dpos[1] = d2; }
    }
    __syncthreads();

    if (t < 32) {
        float a1 = s1s[t] + s1s[t + 32];
        float a2 = s2s[t] + s2s[t + 32];
        float a3 = rs[t] + rs[t + 32];
#pragma unroll
        for (int off = 16; off >= 1; off >>= 1) {
            a1 += __shfl_xor(a1, off);
            a2 += __shfl_xor(a2, off);
            a3 += __shfl_xor(a3, off);
        }
        if (t == 0) {
            float* dst = rowpart + (size_t)blockIdx.x * 6;
            dst[0] = a1;
            dst[1] = a2;
            dst[2] = a3;
            if (part == 0) { dst[3] = dpos[0]; dst[4] = dpos[1]; }
        }
    }
}

__global__ __launch_bounds__(256) void finalize_kernel(const float* __restrict__ rowpart,
                                                       float* __restrict__ out) {
    float c1 = 0.f, c2 = 0.f, rg = 0.f;
    for (int r = threadIdx.x; r < BATCH; r += 256) {
        const float* p0 = rowpart + (size_t)(r * 2) * 6;
        const float* p1 = rowpart + (size_t)(r * 2 + 1) * 6;
        float A1 = p0[0] + p1[0];
        float A2 = p0[1] + p1[1];
        c1 += logf(A1) - p0[3];
        c2 += logf(A2) - p0[4];
        rg += p0[2] + p1[2];
    }
#pragma unroll
    for (int off = 32; off >= 1; off >>= 1) {
        c1 += __shfl_xor(c1, off);
        c2 += __shfl_xor(c2, off);
        rg += __shfl_xor(rg, off);
    }
    __shared__ float buf[4][3];
    int wid = threadIdx.x >> 6, lane = threadIdx.x & 63;
    if (lane == 0) { buf[wid][0] = c1; buf[wid][1] = c2; buf[wid][2] = rg; }
    __syncthreads();
    if (threadIdx.x == 0) {
        float C1 = buf[0][0] + buf[1][0] + buf[2][0] + buf[3][0];
        float C2 = buf[0][1] + buf[1][1] + buf[2][1] + buf[3][1];
        float R  = buf[0][2] + buf[1][2] + buf[2][2] + buf[3][2];
        out[0] = 0.5f * (C1 / (float)BATCH) + 0.5f * (C2 / (float)BATCH);
        out[1] = 0.5f * (R / (float)FLAT);
    }
}

extern "C" void kernel_launch(void* const* d_in, const int* in_sizes, int n_in,
                              void* d_out, int out_size, void* d_ws, size_t ws_size,
                              hipStream_t stream) {
    const int* user = (const int*)d_in[0];
    const int* item = (const int*)d_in[1];
    const int* ridx = (const int*)d_in[2];
    const float* idemb = (const float*)d_in[3];
    const float* vfeat = (const float*)d_in[4];
    const float* W1 = (const float*)d_in[5];
    const float* b1 = (const float*)d_in[6];
    const float* W2 = (const float*)d_in[7];
    const float* b2 = (const float*)d_in[8];
    float* out = (float*)d_out;

    char* ws = (char*)d_ws;
    short* feat_bf  = (short*)(ws);                     // 12,800,000 B
    short* idemb_bf = (short*)(ws + 12800000);          // 38,400,000 B
    float* norms    = (float*)(ws + 51200000);          //    600,000 B
    int*   flags    = (int*)  (ws + 51800000);          //    524,288 B
    float* rowpart  = (float*)(ws + 52324288);          //     49,152 B
    short* w1t      = (short*)(ws + 52373440);          //    131,072 B
    short* w2t      = (short*)(ws + 52504512);          //     65,536 B  (end: 52,570,048)

    const int nridx = in_sizes[2];

    prep0_kernel<<<dim3(512), dim3(256), 0, stream>>>(W1, W2, w1t, w2t, flags);
    fused_prep_kernel<<<dim3(1024), dim3(512), 0, stream>>>(vfeat, w1t, b1, w2t, b2, feat_bf,
                                                            idemb, idemb_bf, norms,
                                                            ridx, nridx, flags);
    contrast_kernel<<<dim3(2 * BATCH), dim3(128), 0, stream>>>(user, item, flags, idemb,
                                                               idemb_bf, norms, feat_bf, rowpart);
    finalize_kernel<<<dim3(1), dim3(256), 0, stream>>>(rowpart, out);
}